// Round 13
// baseline (260.593 us; speedup 1.0000x reference)
//
#include <hip/hip_runtime.h>
#include <hip/hip_bf16.h>

// Problem constants
#define NB 16
#define NN 800
#define NCACHE 128
#define NL 928      // NN + NCACHE
#define CC 1024
#define NH 16
#define HD 64

typedef __attribute__((ext_vector_type(8))) short bf16x8;
typedef __attribute__((ext_vector_type(4))) float f32x4;
typedef __attribute__((ext_vector_type(2))) __bf16 bf2;

__device__ __forceinline__ short f2bf(float x) {
  union { float f; unsigned u; } c; c.f = x;
  unsigned r = c.u + 0x7fffu + ((c.u >> 16) & 1u);
  return (short)(r >> 16);
}

#define GLD_LDS(gp, lp) __builtin_amdgcn_global_load_lds( \
    (__attribute__((address_space(1))) void*)(gp),        \
    (__attribute__((address_space(3))) void*)(lp), 16, 0, 0)

#define BAR() asm volatile("s_barrier" ::: "memory")

// ---------------------------------------------------------------------------
// prep_kv: k_in = bf16(concat(x+xpos, k_t)); v_in = bf16(concat(x, v_t))
// ---------------------------------------------------------------------------
__global__ __launch_bounds__(256) void prep_kv(
    const float* __restrict__ x, const float* __restrict__ xpos,
    const float* __restrict__ ktc, const float* __restrict__ vtc,
    short* __restrict__ k_in, short* __restrict__ v_in) {
  int idx = blockIdx.x * 256 + threadIdx.x;   // 0 .. 16*928*128-1
  int chunk = idx & 127;
  int row = idx >> 7;                          // 0..14847
  int b = row / NL;
  int lr = row - b * NL;
  int c = chunk * 8;
  float vk[8], vv[8];
  if (lr < NN) {
    const float4* px = (const float4*)(x + ((size_t)(b * NN + lr) * CC + c));
    const float4* pp = (const float4*)(xpos + ((size_t)(b * NN + lr) * CC + c));
    float4 x0 = px[0], x1 = px[1], p0 = pp[0], p1 = pp[1];
    vv[0]=x0.x; vv[1]=x0.y; vv[2]=x0.z; vv[3]=x0.w;
    vv[4]=x1.x; vv[5]=x1.y; vv[6]=x1.z; vv[7]=x1.w;
    vk[0]=x0.x+p0.x; vk[1]=x0.y+p0.y; vk[2]=x0.z+p0.z; vk[3]=x0.w+p0.w;
    vk[4]=x1.x+p1.x; vk[5]=x1.y+p1.y; vk[6]=x1.z+p1.z; vk[7]=x1.w+p1.w;
  } else {
    const float4* pk = (const float4*)(ktc + ((size_t)(b * NCACHE + lr - NN) * CC + c));
    const float4* pv = (const float4*)(vtc + ((size_t)(b * NCACHE + lr - NN) * CC + c));
    float4 k0 = pk[0], k1 = pk[1], v0 = pv[0], v1 = pv[1];
    vk[0]=k0.x; vk[1]=k0.y; vk[2]=k0.z; vk[3]=k0.w;
    vk[4]=k1.x; vk[5]=k1.y; vk[6]=k1.z; vk[7]=k1.w;
    vv[0]=v0.x; vv[1]=v0.y; vv[2]=v0.z; vv[3]=v0.w;
    vv[4]=v1.x; vv[5]=v1.y; vv[6]=v1.z; vv[7]=v1.w;
  }
  bf16x8 ok, ov;
#pragma unroll
  for (int i = 0; i < 8; ++i) { ok[i] = f2bf(vk[i]); ov[i] = f2bf(vv[i]); }
  *(bf16x8*)(k_in + (size_t)row * CC + c) = ok;
  *(bf16x8*)(v_in + (size_t)row * CC + c) = ov;
}

// ---------------------------------------------------------------------------
// prep_w v2 (r9, proven): weights -> bf16 MFMA-FRAGMENT-PACKED layout.
//   packed[((t64*NF + nf)*2 + ks)*512 + l*8 + j] =
//       W[nf*16 + (l&15)][t64*64 + ks*32 + (l>>4)*8 + j]
// qk fused NF=128 (cols<1024 Wq*scale, else Wk); Wv NF=64; Wp NF=64.
// ---------------------------------------------------------------------------
__global__ __launch_bounds__(256) void prep_w(
    const float* __restrict__ Wq, const float* __restrict__ Wk,
    const float* __restrict__ Wv, const float* __restrict__ Wp,
    short* __restrict__ wout) {
  int idx = blockIdx.x * 256 + threadIdx.x;  // 0..524287
  int l = idx & 63;
  int frag = idx >> 6;                        // 0..8191
  const float* src;
  int col, t, ks;
  float sc = 1.0f;
  if (frag < 4096) {            // qk packed, NF=128
    ks = frag & 1; int nf = (frag >> 1) & 127; t = frag >> 8;
    col = nf * 16 + (l & 15);
    if (col < 1024) { src = Wq; sc = 0.18033688011112042f; }  // 0.125*log2(e)
    else            { src = Wk; col -= 1024; }
  } else if (frag < 6144) {     // Wv packed, NF=64
    int f2 = frag - 4096; ks = f2 & 1; int nf = (f2 >> 1) & 63; t = f2 >> 7;
    col = nf * 16 + (l & 15); src = Wv;
  } else {                      // Wp packed, NF=64
    int f2 = frag - 6144; ks = f2 & 1; int nf = (f2 >> 1) & 63; t = f2 >> 7;
    col = nf * 16 + (l & 15); src = Wp;
  }
  int k = t * 64 + ks * 32 + ((l >> 4) << 3);
  const float4* p = (const float4*)(src + (size_t)col * CC + k);
  float4 a = p[0], b = p[1];
  bf16x8 o;
  o[0]=f2bf(a.x*sc); o[1]=f2bf(a.y*sc); o[2]=f2bf(a.z*sc); o[3]=f2bf(a.w*sc);
  o[4]=f2bf(b.x*sc); o[5]=f2bf(b.y*sc); o[6]=f2bf(b.z*sc); o[7]=f2bf(b.w*sc);
  *(bf16x8*)(wout + (size_t)idx * 8) = o;
}

// ---------------------------------------------------------------------------
// gemm128 (r12 template, launch_bounds (256,4)): 128x128 tile, BK=64,
// 4 waves (2x2). acc 64 AGPR + 64 VGPR = 128 unified regs/wave -> 4 waves/
// SIMD -> 4 blocks/CU (LDS 4x32KB=128KB). A in LDS (32 KiB dbuf, chunk-XOR
// swizzle, gload_lds). B streamed from packed-fragment global (8 coalesced
// 1KB loads/wave/K-tile, L2-resident). Sync graph unchanged (proven):
// [B(t) reg loads][stage A(t+1)][vmcnt(12)][BAR][8 A ds_reads + 32 MFMA][BAR]
// ---------------------------------------------------------------------------
#define READ_A4(dst, FR0) \
  _Pragma("unroll") \
  for (int fr = 0; fr < 2; ++fr) \
    _Pragma("unroll") \
    for (int ks = 0; ks < 2; ++ks) \
      dst[fr][ks] = *(const bf16x8*)&lds[pb + (wr*64 + ((FR0)+fr)*16 + c)*64 \
                                         + (ks ? xk1 : xk0)];

#define MFMA_HALF(FR0, asrc) \
  _Pragma("unroll") \
  for (int fr = 0; fr < 2; ++fr) \
    _Pragma("unroll") \
    for (int fc = 0; fc < 4; ++fc) \
      _Pragma("unroll") \
      for (int ks = 0; ks < 2; ++ks) \
        acc[(FR0)+fr][fc] = __builtin_amdgcn_mfma_f32_16x16x32_bf16( \
            asrc[fr][ks], bfv[fc][ks], acc[(FR0)+fr][fc], 0, 0, 0);

template<int MODE>
__global__ __launch_bounds__(256, 4) void gemm128(
    const short* __restrict__ A, const short* __restrict__ Bw,
    short* __restrict__ o0, short* __restrict__ o1,
    float* __restrict__ of, const float* __restrict__ bias) {
  __shared__ short lds[16384];   // 32 KiB: parity p at p*8192 shorts, A [128][64]
  const int tid = threadIdx.x;
  const int w = tid >> 6, l = tid & 63;
  const int wr = w >> 1, wc = w & 1;
  const int c = l & 15, g2 = l >> 4;
  const int BNT = (MODE == 2) ? 16 : 8;
  const int NF  = (MODE == 2) ? 128 : 64;
  const int cpx = gridDim.x >> 3;
  const int swz = (blockIdx.x & 7) * cpx + (blockIdx.x >> 3);
  const int bm = swz / BNT, bn = swz % BNT;   // bn-fastest: A panel L2-reused
  const int m0 = bm * 128, n0 = bn * 128;

  const int rbase = w * 32 + (l >> 3);
  const int gcA = (l & 7) ^ (l >> 3);
  const short* As_ = A + (size_t)(m0 + rbase) * CC + gcA * 8;

#define STAGE_A(par, tcol) do { \
    _Pragma("unroll") \
    for (int i = 0; i < 4; ++i) \
      GLD_LDS(As_ + (size_t)(i * 8) * CC + (tcol) * 64, \
              &lds[(par) + (w * 4 + i) * 512]); } while (0)

  const int nfb = (n0 >> 4) + wc * 4;

  const int xk0 = ((g2) ^ (c & 7)) * 8;
  const int xk1 = ((g2 + 4) ^ (c & 7)) * 8;

  f32x4 acc[4][4] = {};

  STAGE_A(0, 0);

#pragma unroll 1
  for (int t = 0; t < 16; ++t) {
    const int pb = (t & 1) << 13;
    const int pn = pb ^ 8192;
    bf16x8 bfv[4][2];
    {
      const short* Bpt = Bw + (((size_t)t * NF + nfb) << 10) + (l << 3);
#pragma unroll
      for (int fc = 0; fc < 4; ++fc)
#pragma unroll
        for (int ks = 0; ks < 2; ++ks)
          bfv[fc][ks] = *(const bf16x8*)(Bpt + ((fc << 1) | ks) * 512);
    }
    if (t < 15) {
      STAGE_A(pn, t + 1);
      asm volatile("s_waitcnt vmcnt(12)" ::: "memory");
    } else {
      asm volatile("s_waitcnt vmcnt(8)" ::: "memory");
    }
    BAR();
    bf16x8 afA[2][2], afB[2][2];
    READ_A4(afA, 0);
    __builtin_amdgcn_s_setprio(1);
    MFMA_HALF(0, afA);
    __builtin_amdgcn_s_setprio(0);
    READ_A4(afB, 2);
    __builtin_amdgcn_s_setprio(1);
    MFMA_HALF(2, afB);
    __builtin_amdgcn_s_setprio(0);
    BAR();
  }

  // epilogue
#pragma unroll
  for (int fr = 0; fr < 4; ++fr)
#pragma unroll
    for (int fc = 0; fc < 4; ++fc) {
      const int row = m0 + wr * 64 + fr * 16 + g2 * 4;
      const int colw = wc * 64 + fc * 16 + c;
      if (MODE == 1) {
        const int col = n0 + colw;
        const float bv = bias[col];
#pragma unroll
        for (int j = 0; j < 4; ++j)
          of[(size_t)(row + j) * CC + col] = acc[fr][fc][j] + bv;
      } else if (MODE == 2) {
        const int col2 = n0 + colw;
        short* base = (col2 < 1024) ? o0 : o1;
        const int col = col2 & 1023;
#pragma unroll
        for (int j = 0; j < 4; ++j)
          base[(size_t)(row + j) * CC + col] = f2bf(acc[fr][fc][j]);
      } else {  // MODE 3: transposed store into vt[(b*16+h)*64+d][NL]
        const int col = n0 + colw;
        const int b = row / NL;
        const int rb = row - b * NL;
        const int vtrow = (b * NH + (col >> 6)) * HD + (col & 63);
        ushort4 pk4;
        pk4.x = (unsigned short)f2bf(acc[fr][fc][0]);
        pk4.y = (unsigned short)f2bf(acc[fr][fc][1]);
        pk4.z = (unsigned short)f2bf(acc[fr][fc][2]);
        pk4.w = (unsigned short)f2bf(acc[fr][fc][3]);
        *(ushort4*)(o0 + (size_t)vtrow * NL + rb) = pk4;
      }
    }
}

// ---------------------------------------------------------------------------
// attn_fwd v6: 5 waves/block x 32 q-rows = 160 rows/block; 5 blocks per
// (b,h) -> 800 = 5*160 exactly, ZERO idle waves (r12 had 3/4 waves idle in
// 1/7 blocks). Staging identical 256-thread pattern under wave-uniform
// tid<256 branch (waves 0-3 stage, all 5 compute). KVBLK=64, no-max
// softmax, K row-permuted + chunk-XOR swizzle, V^T likewise, 32KB LDS dbuf,
// __syncthreads() sync, uniform-exec clamped tail. grid 1280 = 8*160.
// ---------------------------------------------------------------------------
__global__ __launch_bounds__(320, 2) void attn_fwd(
    const short* __restrict__ qb, const short* __restrict__ kbuf,
    const short* __restrict__ vtb, short* __restrict__ ob) {
  __shared__ short smem[2][8192];   // per buf: K [64][64] @0, V^T [64][64] @4096
  const int tid = threadIdx.x;
  const int w = tid >> 6;           // wave 0..4
  const int l = tid & 63;
  const int c = l & 15, g = l >> 4;
  const int swzb = (blockIdx.x & 7) * 160 + (blockIdx.x >> 3);
  const int bh = swzb / 5;
  const int blk5 = swzb - bh * 5;
  const int h = bh & 15, b = bh >> 4;
  const int q0 = blk5 * 160 + w * 32;   // max 640+128 = 768 < 800, all active

  const bool stager = tid < 256;    // waves 0-3 (wave-uniform branch)
  const int r = (tid & 255) >> 3, ch = tid & 7;
  const int b16 = r & 15;
  const int rp = 8 * (b16 >> 2) + (b16 & 3) + 4 * (r >> 4);  // perm within 32
  const int xch = ch ^ (r & 7);
  const int tid8 = (tid & 255) * 8;
  const short* srcKA = kbuf + (size_t)(b * NL + rp) * CC + h * HD + xch * 8;
  const short* srcVA = vtb + (size_t)(bh * HD + r) * NL + xch * 8;
  const short* srcVB = vtb + (size_t)(bh * HD + 32 + r) * NL + xch * 8;

  bf16x8 qf[2][2];
#pragma unroll
  for (int f = 0; f < 2; ++f) {
    const short* qrow = qb + ((size_t)(b * NL + q0 + f * 16 + c) * CC + h * HD + g * 8);
    qf[f][0] = *(const bf16x8*)qrow;
    qf[f][1] = *(const bf16x8*)(qrow + 32);
  }

  int xrc[2];
#pragma unroll
  for (int ks = 0; ks < 2; ++ks)
    xrc[ks] = (((ks * 4 + g) ^ (c & 7)) << 3);

  f32x4 acc[2][4] = {};
  f32x4 ellv[2] = {};

  auto STG_FULL = [&](int buf, int t) {
    if (stager) {
      GLD_LDS(srcKA + (size_t)(t * 64) * CC,      &smem[buf][tid8]);
      GLD_LDS(srcKA + (size_t)(t * 64 + 32) * CC, &smem[buf][2048 + tid8]);
      GLD_LDS(srcVA + t * 64,                     &smem[buf][4096 + tid8]);
      GLD_LDS(srcVB + t * 64,                     &smem[buf][6144 + tid8]);
    }
  };
  auto STG_TAIL = [&](int buf) {
    if (stager) {
      GLD_LDS(srcKA + (size_t)896 * CC, &smem[buf][tid8]);   // kv 896+rp
      const int voff = (xch < 4) ? 896 : 864;   // uniform exec, clamped garbage
      GLD_LDS(srcVA + voff, &smem[buf][4096 + tid8]);
      GLD_LDS(srcVB + voff, &smem[buf][6144 + tid8]);
    }
  };

  auto COMP_FULL = [&](const short* S) {
    bf16x8 kd[4][2], vf[4][2];
#pragma unroll
    for (int si = 0; si < 4; ++si)
#pragma unroll
      for (int ks = 0; ks < 2; ++ks)
        kd[si][ks] = *(const bf16x8*)&S[si * 1024 + c * 64 + xrc[ks]];
#pragma unroll
    for (int n = 0; n < 4; ++n)
#pragma unroll
      for (int ks = 0; ks < 2; ++ks)
        vf[n][ks] = *(const bf16x8*)&S[4096 + (n * 16 + c) * 64 + xrc[ks]];
    __builtin_amdgcn_s_setprio(1);
#pragma unroll
    for (int f = 0; f < 2; ++f) {
      f32x4 z = {0.f, 0.f, 0.f, 0.f};
      f32x4 s[4];
#pragma unroll
      for (int si = 0; si < 4; ++si) {
        s[si] = __builtin_amdgcn_mfma_f32_16x16x32_bf16(kd[si][0], qf[f][0], z, 0, 0, 0);
        s[si] = __builtin_amdgcn_mfma_f32_16x16x32_bf16(kd[si][1], qf[f][1], s[si], 0, 0, 0);
      }
      f32x4 e[4];
#pragma unroll
      for (int si = 0; si < 4; ++si)
#pragma unroll
        for (int j = 0; j < 4; ++j)
          e[si][j] = __builtin_amdgcn_exp2f(s[si][j]);
      ellv[f] += (e[0] + e[1]) + (e[2] + e[3]);
      union { bf2 h2[4]; bf16x8 v; } p0, p1;
      p0.h2[0] = bf2{(__bf16)e[0][0], (__bf16)e[0][1]};
      p0.h2[1] = bf2{(__bf16)e[0][2], (__bf16)e[0][3]};
      p0.h2[2] = bf2{(__bf16)e[1][0], (__bf16)e[1][1]};
      p0.h2[3] = bf2{(__bf16)e[1][2], (__bf16)e[1][3]};
      p1.h2[0] = bf2{(__bf16)e[2][0], (__bf16)e[2][1]};
      p1.h2[1] = bf2{(__bf16)e[2][2], (__bf16)e[2][3]};
      p1.h2[2] = bf2{(__bf16)e[3][0], (__bf16)e[3][1]};
      p1.h2[3] = bf2{(__bf16)e[3][2], (__bf16)e[3][3]};
#pragma unroll
      for (int n = 0; n < 4; ++n) {
        acc[f][n] = __builtin_amdgcn_mfma_f32_16x16x32_bf16(p0.v, vf[n][0], acc[f][n], 0, 0, 0);
        acc[f][n] = __builtin_amdgcn_mfma_f32_16x16x32_bf16(p1.v, vf[n][1], acc[f][n], 0, 0, 0);
      }
    }
    __builtin_amdgcn_s_setprio(0);
  };

  auto COMP_TAIL = [&](const short* S) {
    bf16x8 kd[2][2], vf[4];
#pragma unroll
    for (int si = 0; si < 2; ++si)
#pragma unroll
      for (int ks = 0; ks < 2; ++ks)
        kd[si][ks] = *(const bf16x8*)&S[si * 1024 + c * 64 + xrc[ks]];
#pragma unroll
    for (int n = 0; n < 4; ++n)
      vf[n] = *(const bf16x8*)&S[4096 + (n * 16 + c) * 64 + xrc[0]];
#pragma unroll
    for (int f = 0; f < 2; ++f) {
      f32x4 z = {0.f, 0.f, 0.f, 0.f};
      f32x4 s[2];
#pragma unroll
      for (int si = 0; si < 2; ++si) {
        s[si] = __builtin_amdgcn_mfma_f32_16x16x32_bf16(kd[si][0], qf[f][0], z, 0, 0, 0);
        s[si] = __builtin_amdgcn_mfma_f32_16x16x32_bf16(kd[si][1], qf[f][1], s[si], 0, 0, 0);
      }
      f32x4 e0, e1;
#pragma unroll
      for (int j = 0; j < 4; ++j) { e0[j] = __builtin_amdgcn_exp2f(s[0][j]);
                                    e1[j] = __builtin_amdgcn_exp2f(s[1][j]); }
      ellv[f] += e0 + e1;
      union { bf2 h2[4]; bf16x8 v; } p0;
      p0.h2[0] = bf2{(__bf16)e0[0], (__bf16)e0[1]};
      p0.h2[1] = bf2{(__bf16)e0[2], (__bf16)e0[3]};
      p0.h2[2] = bf2{(__bf16)e1[0], (__bf16)e1[1]};
      p0.h2[3] = bf2{(__bf16)e1[2], (__bf16)e1[3]};
#pragma unroll
      for (int n = 0; n < 4; ++n)
        acc[f][n] = __builtin_amdgcn_mfma_f32_16x16x32_bf16(p0.v, vf[n], acc[f][n], 0, 0, 0);
    }
  };

  STG_FULL(0, 0);
  __syncthreads();
  int buf = 0;
  for (int t = 0; t < 14; ++t) {
    if (t < 13) STG_FULL(buf ^ 1, t + 1);
    else        STG_TAIL(buf ^ 1);
    COMP_FULL(smem[buf]);
    __syncthreads();
    buf ^= 1;
  }
  COMP_TAIL(smem[buf]);
  {
    float rinv[2];
#pragma unroll
    for (int f = 0; f < 2; ++f) {
      float e = (ellv[f][0] + ellv[f][1]) + (ellv[f][2] + ellv[f][3]);
      e += __shfl_xor(e, 16);
      e += __shfl_xor(e, 32);
      rinv[f] = 1.0f / e;
    }
#pragma unroll
    for (int f = 0; f < 2; ++f) {
      float rj[4];
#pragma unroll
      for (int j = 0; j < 4; ++j) rj[j] = __shfl(rinv[f], g * 4 + j);
      short* orow = ob + (size_t)(b * NN + q0 + f * 16 + g * 4) * CC + h * HD + c;
#pragma unroll
      for (int n = 0; n < 4; ++n)
#pragma unroll
        for (int j = 0; j < 4; ++j)
          orow[(size_t)j * CC + n * 16] = f2bf(acc[f][n][j] * rj[j]);
    }
  }
}

// ---------------------------------------------------------------------------
extern "C" void kernel_launch(void* const* d_in, const int* in_sizes, int n_in,
                              void* d_out, int out_size, void* d_ws, size_t ws_size,
                              hipStream_t stream) {
  const float* x    = (const float*)d_in[0];
  const float* xpos = (const float*)d_in[1];
  const float* k_t  = (const float*)d_in[2];
  const float* v_t  = (const float*)d_in[3];
  const float* Wq   = (const float*)d_in[4];
  const float* Wk   = (const float*)d_in[5];
  const float* Wv   = (const float*)d_in[6];
  const float* Wp   = (const float*)d_in[7];
  const float* bp   = (const float*)d_in[8];
  float* out = (float*)d_out;

  // workspace layout (bytes), total 160,432,128
  char* ws = (char*)d_ws;
  short* k_in = (short*)ws;                       // 30,408,704  [16*928,1024] bf16
  short* v_in = (short*)(ws + 30408704);          // 30,408,704
  short* wqb  = (short*)(ws + 60817408);          // packed qk-fused, 4 MB
  short* wvb  = (short*)(ws + 65011712);          // packed Wv, 2 MB
  short* wpb  = (short*)(ws + 67108864);          // packed Wp, 2 MB
  short* qbuf = (short*)(ws + 69206016);          // 30,408,704
  short* kbuf = (short*)(ws + 99614720);          // 30,408,704
  short* vtb  = (short*)(ws + 130023424);         // 30,408,704  vt[(b*16+h)*64+d][928]
  short* attn_o = k_in;   // alias: k_in dead after fused qk GEMM

  prep_kv<<<7424, 256, 0, stream>>>(x, xpos, k_t, v_t, k_in, v_in);
  prep_w<<<2048, 256, 0, stream>>>(Wq, Wk, Wv, Wp, wqb);
  // fused q|k projection (packed B, N=2048)
  gemm128<2><<<1856, 256, 0, stream>>>(k_in, wqb, qbuf, kbuf, nullptr, nullptr);
  // v projection with fused transpose into vt (packed B)
  gemm128<3><<<928, 256, 0, stream>>>(v_in, wvb, vtb, nullptr, nullptr, nullptr);
  attn_fwd<<<1280, 320, 0, stream>>>(qbuf, kbuf, vtb, attn_o);
  gemm128<1><<<800, 256, 0, stream>>>(attn_o, wpb, nullptr, nullptr, out, bp);
}

// Round 14
// 248.370 us; speedup vs baseline: 1.0492x; 1.0492x over previous
//
#include <hip/hip_runtime.h>
#include <hip/hip_bf16.h>

// Problem constants
#define NB 16
#define NN 800
#define NCACHE 128
#define NL 928      // NN + NCACHE
#define CC 1024
#define NH 16
#define HD 64

typedef __attribute__((ext_vector_type(8))) short bf16x8;
typedef __attribute__((ext_vector_type(4))) float f32x4;
typedef __attribute__((ext_vector_type(2))) __bf16 bf2;

__device__ __forceinline__ short f2bf(float x) {
  union { float f; unsigned u; } c; c.f = x;
  unsigned r = c.u + 0x7fffu + ((c.u >> 16) & 1u);
  return (short)(r >> 16);
}

#define GLD_LDS(gp, lp) __builtin_amdgcn_global_load_lds( \
    (__attribute__((address_space(1))) void*)(gp),        \
    (__attribute__((address_space(3))) void*)(lp), 16, 0, 0)

#define BAR() asm volatile("s_barrier" ::: "memory")

// ---------------------------------------------------------------------------
// prep_kv: k_in = bf16(concat(x+xpos, k_t)); v_in = bf16(concat(x, v_t))
// ---------------------------------------------------------------------------
__global__ __launch_bounds__(256) void prep_kv(
    const float* __restrict__ x, const float* __restrict__ xpos,
    const float* __restrict__ ktc, const float* __restrict__ vtc,
    short* __restrict__ k_in, short* __restrict__ v_in) {
  int idx = blockIdx.x * 256 + threadIdx.x;   // 0 .. 16*928*128-1
  int chunk = idx & 127;
  int row = idx >> 7;                          // 0..14847
  int b = row / NL;
  int lr = row - b * NL;
  int c = chunk * 8;
  float vk[8], vv[8];
  if (lr < NN) {
    const float4* px = (const float4*)(x + ((size_t)(b * NN + lr) * CC + c));
    const float4* pp = (const float4*)(xpos + ((size_t)(b * NN + lr) * CC + c));
    float4 x0 = px[0], x1 = px[1], p0 = pp[0], p1 = pp[1];
    vv[0]=x0.x; vv[1]=x0.y; vv[2]=x0.z; vv[3]=x0.w;
    vv[4]=x1.x; vv[5]=x1.y; vv[6]=x1.z; vv[7]=x1.w;
    vk[0]=x0.x+p0.x; vk[1]=x0.y+p0.y; vk[2]=x0.z+p0.z; vk[3]=x0.w+p0.w;
    vk[4]=x1.x+p1.x; vk[5]=x1.y+p1.y; vk[6]=x1.z+p1.z; vk[7]=x1.w+p1.w;
  } else {
    const float4* pk = (const float4*)(ktc + ((size_t)(b * NCACHE + lr - NN) * CC + c));
    const float4* pv = (const float4*)(vtc + ((size_t)(b * NCACHE + lr - NN) * CC + c));
    float4 k0 = pk[0], k1 = pk[1], v0 = pv[0], v1 = pv[1];
    vk[0]=k0.x; vk[1]=k0.y; vk[2]=k0.z; vk[3]=k0.w;
    vk[4]=k1.x; vk[5]=k1.y; vk[6]=k1.z; vk[7]=k1.w;
    vv[0]=v0.x; vv[1]=v0.y; vv[2]=v0.z; vv[3]=v0.w;
    vv[4]=v1.x; vv[5]=v1.y; vv[6]=v1.z; vv[7]=v1.w;
  }
  bf16x8 ok, ov;
#pragma unroll
  for (int i = 0; i < 8; ++i) { ok[i] = f2bf(vk[i]); ov[i] = f2bf(vv[i]); }
  *(bf16x8*)(k_in + (size_t)row * CC + c) = ok;
  *(bf16x8*)(v_in + (size_t)row * CC + c) = ov;
}

// ---------------------------------------------------------------------------
// prep_w v2 (r9, proven): weights -> bf16 MFMA-FRAGMENT-PACKED layout.
//   packed[((t64*NF + nf)*2 + ks)*512 + l*8 + j] =
//       W[nf*16 + (l&15)][t64*64 + ks*32 + (l>>4)*8 + j]
// qk fused NF=128 (cols<1024 Wq*scale, else Wk); Wv NF=64; Wp NF=64.
// ---------------------------------------------------------------------------
__global__ __launch_bounds__(256) void prep_w(
    const float* __restrict__ Wq, const float* __restrict__ Wk,
    const float* __restrict__ Wv, const float* __restrict__ Wp,
    short* __restrict__ wout) {
  int idx = blockIdx.x * 256 + threadIdx.x;  // 0..524287
  int l = idx & 63;
  int frag = idx >> 6;                        // 0..8191
  const float* src;
  int col, t, ks;
  float sc = 1.0f;
  if (frag < 4096) {            // qk packed, NF=128
    ks = frag & 1; int nf = (frag >> 1) & 127; t = frag >> 8;
    col = nf * 16 + (l & 15);
    if (col < 1024) { src = Wq; sc = 0.18033688011112042f; }  // 0.125*log2(e)
    else            { src = Wk; col -= 1024; }
  } else if (frag < 6144) {     // Wv packed, NF=64
    int f2 = frag - 4096; ks = f2 & 1; int nf = (f2 >> 1) & 63; t = f2 >> 7;
    col = nf * 16 + (l & 15); src = Wv;
  } else {                      // Wp packed, NF=64
    int f2 = frag - 6144; ks = f2 & 1; int nf = (f2 >> 1) & 63; t = f2 >> 7;
    col = nf * 16 + (l & 15); src = Wp;
  }
  int k = t * 64 + ks * 32 + ((l >> 4) << 3);
  const float4* p = (const float4*)(src + (size_t)col * CC + k);
  float4 a = p[0], b = p[1];
  bf16x8 o;
  o[0]=f2bf(a.x*sc); o[1]=f2bf(a.y*sc); o[2]=f2bf(a.z*sc); o[3]=f2bf(a.w*sc);
  o[4]=f2bf(b.x*sc); o[5]=f2bf(b.y*sc); o[6]=f2bf(b.z*sc); o[7]=f2bf(b.w*sc);
  *(bf16x8*)(wout + (size_t)idx * 8) = o;
}

// ---------------------------------------------------------------------------
// gemm128 (r13, proven): 128x128 tile, BK=64, 4 waves (2x2), (256,4) ->
// 4 blocks/CU (128 unified regs/wave, LDS 4x32KB). A in LDS (32 KiB dbuf,
// chunk-XOR swizzle, gload_lds). B streamed from packed-fragment global.
// [B(t) reg loads][stage A(t+1)][vmcnt(12)][BAR][8 A ds_reads + 32 MFMA][BAR]
// ---------------------------------------------------------------------------
#define READ_A4(dst, FR0) \
  _Pragma("unroll") \
  for (int fr = 0; fr < 2; ++fr) \
    _Pragma("unroll") \
    for (int ks = 0; ks < 2; ++ks) \
      dst[fr][ks] = *(const bf16x8*)&lds[pb + (wr*64 + ((FR0)+fr)*16 + c)*64 \
                                         + (ks ? xk1 : xk0)];

#define MFMA_HALF(FR0, asrc) \
  _Pragma("unroll") \
  for (int fr = 0; fr < 2; ++fr) \
    _Pragma("unroll") \
    for (int fc = 0; fc < 4; ++fc) \
      _Pragma("unroll") \
      for (int ks = 0; ks < 2; ++ks) \
        acc[(FR0)+fr][fc] = __builtin_amdgcn_mfma_f32_16x16x32_bf16( \
            asrc[fr][ks], bfv[fc][ks], acc[(FR0)+fr][fc], 0, 0, 0);

template<int MODE>
__global__ __launch_bounds__(256, 4) void gemm128(
    const short* __restrict__ A, const short* __restrict__ Bw,
    short* __restrict__ o0, short* __restrict__ o1,
    float* __restrict__ of, const float* __restrict__ bias) {
  __shared__ short lds[16384];   // 32 KiB: parity p at p*8192 shorts, A [128][64]
  const int tid = threadIdx.x;
  const int w = tid >> 6, l = tid & 63;
  const int wr = w >> 1, wc = w & 1;
  const int c = l & 15, g2 = l >> 4;
  const int BNT = (MODE == 2) ? 16 : 8;
  const int NF  = (MODE == 2) ? 128 : 64;
  const int cpx = gridDim.x >> 3;
  const int swz = (blockIdx.x & 7) * cpx + (blockIdx.x >> 3);
  const int bm = swz / BNT, bn = swz % BNT;   // bn-fastest: A panel L2-reused
  const int m0 = bm * 128, n0 = bn * 128;

  const int rbase = w * 32 + (l >> 3);
  const int gcA = (l & 7) ^ (l >> 3);
  const short* As_ = A + (size_t)(m0 + rbase) * CC + gcA * 8;

#define STAGE_A(par, tcol) do { \
    _Pragma("unroll") \
    for (int i = 0; i < 4; ++i) \
      GLD_LDS(As_ + (size_t)(i * 8) * CC + (tcol) * 64, \
              &lds[(par) + (w * 4 + i) * 512]); } while (0)

  const int nfb = (n0 >> 4) + wc * 4;

  const int xk0 = ((g2) ^ (c & 7)) * 8;
  const int xk1 = ((g2 + 4) ^ (c & 7)) * 8;

  f32x4 acc[4][4] = {};

  STAGE_A(0, 0);

#pragma unroll 1
  for (int t = 0; t < 16; ++t) {
    const int pb = (t & 1) << 13;
    const int pn = pb ^ 8192;
    bf16x8 bfv[4][2];
    {
      const short* Bpt = Bw + (((size_t)t * NF + nfb) << 10) + (l << 3);
#pragma unroll
      for (int fc = 0; fc < 4; ++fc)
#pragma unroll
        for (int ks = 0; ks < 2; ++ks)
          bfv[fc][ks] = *(const bf16x8*)(Bpt + ((fc << 1) | ks) * 512);
    }
    if (t < 15) {
      STAGE_A(pn, t + 1);
      asm volatile("s_waitcnt vmcnt(12)" ::: "memory");
    } else {
      asm volatile("s_waitcnt vmcnt(8)" ::: "memory");
    }
    BAR();
    bf16x8 afA[2][2], afB[2][2];
    READ_A4(afA, 0);
    __builtin_amdgcn_s_setprio(1);
    MFMA_HALF(0, afA);
    __builtin_amdgcn_s_setprio(0);
    READ_A4(afB, 2);
    __builtin_amdgcn_s_setprio(1);
    MFMA_HALF(2, afB);
    __builtin_amdgcn_s_setprio(0);
    BAR();
  }

  // epilogue
#pragma unroll
  for (int fr = 0; fr < 4; ++fr)
#pragma unroll
    for (int fc = 0; fc < 4; ++fc) {
      const int row = m0 + wr * 64 + fr * 16 + g2 * 4;
      const int colw = wc * 64 + fc * 16 + c;
      if (MODE == 1) {
        const int col = n0 + colw;
        const float bv = bias[col];
#pragma unroll
        for (int j = 0; j < 4; ++j)
          of[(size_t)(row + j) * CC + col] = acc[fr][fc][j] + bv;
      } else if (MODE == 2) {
        const int col2 = n0 + colw;
        short* base = (col2 < 1024) ? o0 : o1;
        const int col = col2 & 1023;
#pragma unroll
        for (int j = 0; j < 4; ++j)
          base[(size_t)(row + j) * CC + col] = f2bf(acc[fr][fc][j]);
      } else {  // MODE 3: transposed store into vt[(b*16+h)*64+d][NL]
        const int col = n0 + colw;
        const int b = row / NL;
        const int rb = row - b * NL;
        const int vtrow = (b * NH + (col >> 6)) * HD + (col & 63);
        ushort4 pk4;
        pk4.x = (unsigned short)f2bf(acc[fr][fc][0]);
        pk4.y = (unsigned short)f2bf(acc[fr][fc][1]);
        pk4.z = (unsigned short)f2bf(acc[fr][fc][2]);
        pk4.w = (unsigned short)f2bf(acc[fr][fc][3]);
        *(ushort4*)(o0 + (size_t)vtrow * NL + rb) = pk4;
      }
    }
}

// ---------------------------------------------------------------------------
// attn_fwd v5.1 (r11/r12, proven): KVBLK=64, 4 waves x 32 q-rows, no-max
// softmax, K row-permuted + chunk-XOR swizzle, V^T likewise, 32KB LDS dbuf,
// __syncthreads() sync, uniform-exec clamped tail. grid 1792 = 8*224.
// ---------------------------------------------------------------------------
__global__ __launch_bounds__(256, 3) void attn_fwd(
    const short* __restrict__ qb, const short* __restrict__ kbuf,
    const short* __restrict__ vtb, short* __restrict__ ob) {
  __shared__ short smem[2][8192];   // per buf: K [64][64] @0, V^T [64][64] @4096
  const int tid = threadIdx.x;
  const int w = tid >> 6;           // wave 0..3
  const int l = tid & 63;
  const int c = l & 15, g = l >> 4;
  const int swzb = (blockIdx.x & 7) * 224 + (blockIdx.x >> 3);
  const int bh = swzb / 7;
  const int blk7 = swzb - bh * 7;
  const int h = bh & 15, b = bh >> 4;
  const int q0 = blk7 * 128 + w * 32;
  const bool active = q0 < NN;

  const int r = tid >> 3, ch = tid & 7;
  const int b16 = r & 15;
  const int rp = 8 * (b16 >> 2) + (b16 & 3) + 4 * (r >> 4);  // perm within 32
  const int xch = ch ^ (r & 7);
  const int tid8 = tid * 8;
  const short* srcKA = kbuf + (size_t)(b * NL + rp) * CC + h * HD + xch * 8;
  const short* srcVA = vtb + (size_t)(bh * HD + r) * NL + xch * 8;
  const short* srcVB = vtb + (size_t)(bh * HD + 32 + r) * NL + xch * 8;

  bf16x8 qf[2][2];
  if (active) {
#pragma unroll
    for (int f = 0; f < 2; ++f) {
      const short* qrow = qb + ((size_t)(b * NL + q0 + f * 16 + c) * CC + h * HD + g * 8);
      qf[f][0] = *(const bf16x8*)qrow;
      qf[f][1] = *(const bf16x8*)(qrow + 32);
    }
  }

  int xrc[2];
#pragma unroll
  for (int ks = 0; ks < 2; ++ks)
    xrc[ks] = (((ks * 4 + g) ^ (c & 7)) << 3);

  f32x4 acc[2][4] = {};
  f32x4 ellv[2] = {};

  auto STG_FULL = [&](int buf, int t) {
    GLD_LDS(srcKA + (size_t)(t * 64) * CC,      &smem[buf][tid8]);
    GLD_LDS(srcKA + (size_t)(t * 64 + 32) * CC, &smem[buf][2048 + tid8]);
    GLD_LDS(srcVA + t * 64,                     &smem[buf][4096 + tid8]);
    GLD_LDS(srcVB + t * 64,                     &smem[buf][6144 + tid8]);
  };
  auto STG_TAIL = [&](int buf) {
    GLD_LDS(srcKA + (size_t)896 * CC, &smem[buf][tid8]);   // kv 896+rp
    const int voff = (xch < 4) ? 896 : 864;   // uniform exec, clamped garbage
    GLD_LDS(srcVA + voff, &smem[buf][4096 + tid8]);
    GLD_LDS(srcVB + voff, &smem[buf][6144 + tid8]);
  };

  auto COMP_FULL = [&](const short* S) {
    bf16x8 kd[4][2], vf[4][2];
#pragma unroll
    for (int si = 0; si < 4; ++si)
#pragma unroll
      for (int ks = 0; ks < 2; ++ks)
        kd[si][ks] = *(const bf16x8*)&S[si * 1024 + c * 64 + xrc[ks]];
#pragma unroll
    for (int n = 0; n < 4; ++n)
#pragma unroll
      for (int ks = 0; ks < 2; ++ks)
        vf[n][ks] = *(const bf16x8*)&S[4096 + (n * 16 + c) * 64 + xrc[ks]];
    __builtin_amdgcn_s_setprio(1);
#pragma unroll
    for (int f = 0; f < 2; ++f) {
      f32x4 z = {0.f, 0.f, 0.f, 0.f};
      f32x4 s[4];
#pragma unroll
      for (int si = 0; si < 4; ++si) {
        s[si] = __builtin_amdgcn_mfma_f32_16x16x32_bf16(kd[si][0], qf[f][0], z, 0, 0, 0);
        s[si] = __builtin_amdgcn_mfma_f32_16x16x32_bf16(kd[si][1], qf[f][1], s[si], 0, 0, 0);
      }
      f32x4 e[4];
#pragma unroll
      for (int si = 0; si < 4; ++si)
#pragma unroll
        for (int j = 0; j < 4; ++j)
          e[si][j] = __builtin_amdgcn_exp2f(s[si][j]);
      ellv[f] += (e[0] + e[1]) + (e[2] + e[3]);
      union { bf2 h2[4]; bf16x8 v; } p0, p1;
      p0.h2[0] = bf2{(__bf16)e[0][0], (__bf16)e[0][1]};
      p0.h2[1] = bf2{(__bf16)e[0][2], (__bf16)e[0][3]};
      p0.h2[2] = bf2{(__bf16)e[1][0], (__bf16)e[1][1]};
      p0.h2[3] = bf2{(__bf16)e[1][2], (__bf16)e[1][3]};
      p1.h2[0] = bf2{(__bf16)e[2][0], (__bf16)e[2][1]};
      p1.h2[1] = bf2{(__bf16)e[2][2], (__bf16)e[2][3]};
      p1.h2[2] = bf2{(__bf16)e[3][0], (__bf16)e[3][1]};
      p1.h2[3] = bf2{(__bf16)e[3][2], (__bf16)e[3][3]};
#pragma unroll
      for (int n = 0; n < 4; ++n) {
        acc[f][n] = __builtin_amdgcn_mfma_f32_16x16x32_bf16(p0.v, vf[n][0], acc[f][n], 0, 0, 0);
        acc[f][n] = __builtin_amdgcn_mfma_f32_16x16x32_bf16(p1.v, vf[n][1], acc[f][n], 0, 0, 0);
      }
    }
    __builtin_amdgcn_s_setprio(0);
  };

  auto COMP_TAIL = [&](const short* S) {
    bf16x8 kd[2][2], vf[4];
#pragma unroll
    for (int si = 0; si < 2; ++si)
#pragma unroll
      for (int ks = 0; ks < 2; ++ks)
        kd[si][ks] = *(const bf16x8*)&S[si * 1024 + c * 64 + xrc[ks]];
#pragma unroll
    for (int n = 0; n < 4; ++n)
      vf[n] = *(const bf16x8*)&S[4096 + (n * 16 + c) * 64 + xrc[0]];
#pragma unroll
    for (int f = 0; f < 2; ++f) {
      f32x4 z = {0.f, 0.f, 0.f, 0.f};
      f32x4 s[2];
#pragma unroll
      for (int si = 0; si < 2; ++si) {
        s[si] = __builtin_amdgcn_mfma_f32_16x16x32_bf16(kd[si][0], qf[f][0], z, 0, 0, 0);
        s[si] = __builtin_amdgcn_mfma_f32_16x16x32_bf16(kd[si][1], qf[f][1], s[si], 0, 0, 0);
      }
      f32x4 e0, e1;
#pragma unroll
      for (int j = 0; j < 4; ++j) { e0[j] = __builtin_amdgcn_exp2f(s[0][j]);
                                    e1[j] = __builtin_amdgcn_exp2f(s[1][j]); }
      ellv[f] += e0 + e1;
      union { bf2 h2[4]; bf16x8 v; } p0;
      p0.h2[0] = bf2{(__bf16)e0[0], (__bf16)e0[1]};
      p0.h2[1] = bf2{(__bf16)e0[2], (__bf16)e0[3]};
      p0.h2[2] = bf2{(__bf16)e1[0], (__bf16)e1[1]};
      p0.h2[3] = bf2{(__bf16)e1[2], (__bf16)e1[3]};
#pragma unroll
      for (int n = 0; n < 4; ++n)
        acc[f][n] = __builtin_amdgcn_mfma_f32_16x16x32_bf16(p0.v, vf[n], acc[f][n], 0, 0, 0);
    }
  };

  STG_FULL(0, 0);
  __syncthreads();
  int buf = 0;
  for (int t = 0; t < 14; ++t) {
    if (t < 13) STG_FULL(buf ^ 1, t + 1);
    else        STG_TAIL(buf ^ 1);
    if (active) COMP_FULL(smem[buf]);
    __syncthreads();
    buf ^= 1;
  }
  if (active) {
    COMP_TAIL(smem[buf]);
    float rinv[2];
#pragma unroll
    for (int f = 0; f < 2; ++f) {
      float e = (ellv[f][0] + ellv[f][1]) + (ellv[f][2] + ellv[f][3]);
      e += __shfl_xor(e, 16);
      e += __shfl_xor(e, 32);
      rinv[f] = 1.0f / e;
    }
#pragma unroll
    for (int f = 0; f < 2; ++f) {
      float rj[4];
#pragma unroll
      for (int j = 0; j < 4; ++j) rj[j] = __shfl(rinv[f], g * 4 + j);
      short* orow = ob + (size_t)(b * NN + q0 + f * 16 + g * 4) * CC + h * HD + c;
#pragma unroll
      for (int n = 0; n < 4; ++n)
#pragma unroll
        for (int j = 0; j < 4; ++j)
          orow[(size_t)j * CC + n * 16] = f2bf(acc[f][n][j] * rj[j]);
    }
  }
}

// ---------------------------------------------------------------------------
extern "C" void kernel_launch(void* const* d_in, const int* in_sizes, int n_in,
                              void* d_out, int out_size, void* d_ws, size_t ws_size,
                              hipStream_t stream) {
  const float* x    = (const float*)d_in[0];
  const float* xpos = (const float*)d_in[1];
  const float* k_t  = (const float*)d_in[2];
  const float* v_t  = (const float*)d_in[3];
  const float* Wq   = (const float*)d_in[4];
  const float* Wk   = (const float*)d_in[5];
  const float* Wv   = (const float*)d_in[6];
  const float* Wp   = (const float*)d_in[7];
  const float* bp   = (const float*)d_in[8];
  float* out = (float*)d_out;

  // workspace layout (bytes), total 160,432,128
  char* ws = (char*)d_ws;
  short* k_in = (short*)ws;                       // 30,408,704  [16*928,1024] bf16
  short* v_in = (short*)(ws + 30408704);          // 30,408,704
  short* wqb  = (short*)(ws + 60817408);          // packed qk-fused, 4 MB
  short* wvb  = (short*)(ws + 65011712);          // packed Wv, 2 MB
  short* wpb  = (short*)(ws + 67108864);          // packed Wp, 2 MB
  short* qbuf = (short*)(ws + 69206016);          // 30,408,704
  short* kbuf = (short*)(ws + 99614720);          // 30,408,704
  short* vtb  = (short*)(ws + 130023424);         // 30,408,704  vt[(b*16+h)*64+d][928]
  short* attn_o = k_in;   // alias: k_in dead after fused qk GEMM

  prep_kv<<<7424, 256, 0, stream>>>(x, xpos, k_t, v_t, k_in, v_in);
  prep_w<<<2048, 256, 0, stream>>>(Wq, Wk, Wv, Wp, wqb);
  // fused q|k projection (packed B, N=2048)
  gemm128<2><<<1856, 256, 0, stream>>>(k_in, wqb, qbuf, kbuf, nullptr, nullptr);
  // v projection with fused transpose into vt (packed B)
  gemm128<3><<<928, 256, 0, stream>>>(v_in, wvb, vtb, nullptr, nullptr, nullptr);
  attn_fwd<<<1792, 256, 0, stream>>>(qbuf, kbuf, vtb, attn_o);
  gemm128<1><<<800, 256, 0, stream>>>(attn_o, wpb, nullptr, nullptr, out, bp);
}

// Round 15
// 234.737 us; speedup vs baseline: 1.1101x; 1.0581x over previous
//
#include <hip/hip_runtime.h>
#include <hip/hip_bf16.h>

// Problem constants
#define NB 16
#define NN 800
#define NCACHE 128
#define NL 928      // NN + NCACHE
#define CC 1024
#define NH 16
#define HD 64

typedef __attribute__((ext_vector_type(8))) short bf16x8;
typedef __attribute__((ext_vector_type(4))) float f32x4;
typedef __attribute__((ext_vector_type(2))) __bf16 bf2;

__device__ __forceinline__ short f2bf(float x) {
  union { float f; unsigned u; } c; c.f = x;
  unsigned r = c.u + 0x7fffu + ((c.u >> 16) & 1u);
  return (short)(r >> 16);
}

#define GLD_LDS(gp, lp) __builtin_amdgcn_global_load_lds( \
    (__attribute__((address_space(1))) void*)(gp),        \
    (__attribute__((address_space(3))) void*)(lp), 16, 0, 0)

#define BAR() asm volatile("s_barrier" ::: "memory")

// ---------------------------------------------------------------------------
// prep_all: merged prep_w (blocks 0..2047) + prep_kv (blocks 2048..9471).
// Independent elementwise work; merging pays launch/tail cost once.
// ---------------------------------------------------------------------------
__global__ __launch_bounds__(256) void prep_all(
    const float* __restrict__ x, const float* __restrict__ xpos,
    const float* __restrict__ ktc, const float* __restrict__ vtc,
    const float* __restrict__ Wq, const float* __restrict__ Wk,
    const float* __restrict__ Wv, const float* __restrict__ Wp,
    short* __restrict__ k_in, short* __restrict__ v_in,
    short* __restrict__ wout) {
  if (blockIdx.x < 2048) {
    // ---- prep_w v2 (r9, proven): MFMA-fragment-packed weights ----
    int idx = blockIdx.x * 256 + threadIdx.x;  // 0..524287
    int l = idx & 63;
    int frag = idx >> 6;                        // 0..8191
    const float* src;
    int col, t, ks;
    float sc = 1.0f;
    if (frag < 4096) {            // qk packed, NF=128
      ks = frag & 1; int nf = (frag >> 1) & 127; t = frag >> 8;
      col = nf * 16 + (l & 15);
      if (col < 1024) { src = Wq; sc = 0.18033688011112042f; }  // 0.125*log2(e)
      else            { src = Wk; col -= 1024; }
    } else if (frag < 6144) {     // Wv packed, NF=64
      int f2 = frag - 4096; ks = f2 & 1; int nf = (f2 >> 1) & 63; t = f2 >> 7;
      col = nf * 16 + (l & 15); src = Wv;
    } else {                      // Wp packed, NF=64
      int f2 = frag - 6144; ks = f2 & 1; int nf = (f2 >> 1) & 63; t = f2 >> 7;
      col = nf * 16 + (l & 15); src = Wp;
    }
    int k = t * 64 + ks * 32 + ((l >> 4) << 3);
    const float4* p = (const float4*)(src + (size_t)col * CC + k);
    float4 a = p[0], b = p[1];
    bf16x8 o;
    o[0]=f2bf(a.x*sc); o[1]=f2bf(a.y*sc); o[2]=f2bf(a.z*sc); o[3]=f2bf(a.w*sc);
    o[4]=f2bf(b.x*sc); o[5]=f2bf(b.y*sc); o[6]=f2bf(b.z*sc); o[7]=f2bf(b.w*sc);
    *(bf16x8*)(wout + (size_t)idx * 8) = o;
  } else {
    // ---- prep_kv (proven) ----
    int idx = (blockIdx.x - 2048) * 256 + threadIdx.x;   // 0 .. 16*928*128-1
    int chunk = idx & 127;
    int row = idx >> 7;                          // 0..14847
    int b = row / NL;
    int lr = row - b * NL;
    int c = chunk * 8;
    float vk[8], vv[8];
    if (lr < NN) {
      const float4* px = (const float4*)(x + ((size_t)(b * NN + lr) * CC + c));
      const float4* pp = (const float4*)(xpos + ((size_t)(b * NN + lr) * CC + c));
      float4 x0 = px[0], x1 = px[1], p0 = pp[0], p1 = pp[1];
      vv[0]=x0.x; vv[1]=x0.y; vv[2]=x0.z; vv[3]=x0.w;
      vv[4]=x1.x; vv[5]=x1.y; vv[6]=x1.z; vv[7]=x1.w;
      vk[0]=x0.x+p0.x; vk[1]=x0.y+p0.y; vk[2]=x0.z+p0.z; vk[3]=x0.w+p0.w;
      vk[4]=x1.x+p1.x; vk[5]=x1.y+p1.y; vk[6]=x1.z+p1.z; vk[7]=x1.w+p1.w;
    } else {
      const float4* pk = (const float4*)(ktc + ((size_t)(b * NCACHE + lr - NN) * CC + c));
      const float4* pv = (const float4*)(vtc + ((size_t)(b * NCACHE + lr - NN) * CC + c));
      float4 k0 = pk[0], k1 = pk[1], v0 = pv[0], v1 = pv[1];
      vk[0]=k0.x; vk[1]=k0.y; vk[2]=k0.z; vk[3]=k0.w;
      vk[4]=k1.x; vk[5]=k1.y; vk[6]=k1.z; vk[7]=k1.w;
      vv[0]=v0.x; vv[1]=v0.y; vv[2]=v0.z; vv[3]=v0.w;
      vv[4]=v1.x; vv[5]=v1.y; vv[6]=v1.z; vv[7]=v1.w;
    }
    bf16x8 ok, ov;
#pragma unroll
    for (int i = 0; i < 8; ++i) { ok[i] = f2bf(vk[i]); ov[i] = f2bf(vv[i]); }
    *(bf16x8*)(k_in + (size_t)row * CC + c) = ok;
    *(bf16x8*)(v_in + (size_t)row * CC + c) = ov;
  }
}

// ---------------------------------------------------------------------------
// gemm128 core loop (r13/r14, proven): 128x128 tile, BK=64, 4 waves (2x2),
// (256,4). A in LDS (32 KiB dbuf, chunk-XOR swizzle, gload_lds). B streamed
// from packed-fragment global. [B(t) reg loads][stage A(t+1)][vmcnt(12)]
// [BAR][8 A ds_reads + 32 MFMA][BAR].
// ---------------------------------------------------------------------------
#define READ_A4(dst, FR0) \
  _Pragma("unroll") \
  for (int fr = 0; fr < 2; ++fr) \
    _Pragma("unroll") \
    for (int ks = 0; ks < 2; ++ks) \
      dst[fr][ks] = *(const bf16x8*)&lds[pb + (wr*64 + ((FR0)+fr)*16 + c)*64 \
                                         + (ks ? xk1 : xk0)];

#define MFMA_HALF(FR0, asrc) \
  _Pragma("unroll") \
  for (int fr = 0; fr < 2; ++fr) \
    _Pragma("unroll") \
    for (int fc = 0; fc < 4; ++fc) \
      _Pragma("unroll") \
      for (int ks = 0; ks < 2; ++ks) \
        acc[(FR0)+fr][fc] = __builtin_amdgcn_mfma_f32_16x16x32_bf16( \
            asrc[fr][ks], bfv[fc][ks], acc[(FR0)+fr][fc], 0, 0, 0);

// main-loop body shared by gemm_qkv and gemm_proj (A, Bw, NF, m0, n0 in scope)
#define GEMM_MAIN_LOOP() \
  const int rbase = w * 32 + (l >> 3); \
  const int gcA = (l & 7) ^ (l >> 3); \
  const short* As_ = A + (size_t)(m0 + rbase) * CC + gcA * 8; \
  const int nfb = (n0 >> 4) + wc * 4; \
  const int xk0 = ((g2) ^ (c & 7)) * 8; \
  const int xk1 = ((g2 + 4) ^ (c & 7)) * 8; \
  STAGE_A(0, 0); \
  _Pragma("unroll 1") \
  for (int t = 0; t < 16; ++t) { \
    const int pb = (t & 1) << 13; \
    const int pn = pb ^ 8192; \
    bf16x8 bfv[4][2]; \
    { \
      const short* Bpt = Bw + (((size_t)t * NF + nfb) << 10) + (l << 3); \
      _Pragma("unroll") \
      for (int fc = 0; fc < 4; ++fc) \
        _Pragma("unroll") \
        for (int ks = 0; ks < 2; ++ks) \
          bfv[fc][ks] = *(const bf16x8*)(Bpt + ((fc << 1) | ks) * 512); \
    } \
    if (t < 15) { \
      STAGE_A(pn, t + 1); \
      asm volatile("s_waitcnt vmcnt(12)" ::: "memory"); \
    } else { \
      asm volatile("s_waitcnt vmcnt(8)" ::: "memory"); \
    } \
    BAR(); \
    bf16x8 afA[2][2], afB[2][2]; \
    READ_A4(afA, 0); \
    __builtin_amdgcn_s_setprio(1); \
    MFMA_HALF(0, afA); \
    __builtin_amdgcn_s_setprio(0); \
    READ_A4(afB, 2); \
    __builtin_amdgcn_s_setprio(1); \
    MFMA_HALF(2, afB); \
    __builtin_amdgcn_s_setprio(0); \
    BAR(); \
  }

#define STAGE_A(par, tcol) do { \
    _Pragma("unroll") \
    for (int i = 0; i < 4; ++i) \
      GLD_LDS(As_ + (size_t)(i * 8) * CC + (tcol) * 64, \
              &lds[(par) + (w * 4 + i) * 512]); } while (0)

// ---------------------------------------------------------------------------
// gemm_qkv: MERGED qk-projection (blocks 0..1855, MODE2 path) + v-projection
// (blocks 1856..2783, MODE3 path). Independent GEMMs; merging overlaps the
// v-GEMM with the qk tail (one ramp/tail instead of two). Both paths are
// byte-identical to the proven r13/r14 templates.
// ---------------------------------------------------------------------------
__global__ __launch_bounds__(256, 4) void gemm_qkv(
    const short* __restrict__ k_in, const short* __restrict__ v_in,
    const short* __restrict__ wqb, const short* __restrict__ wvb,
    short* __restrict__ qbuf, short* __restrict__ kbuf,
    short* __restrict__ vtb) {
  __shared__ short lds[16384];   // 32 KiB: parity p at p*8192 shorts, A [128][64]
  const int tid = threadIdx.x;
  const int w = tid >> 6, l = tid & 63;
  const int wr = w >> 1, wc = w & 1;
  const int c = l & 15, g2 = l >> 4;
  const bool isqk = blockIdx.x < 1856;
  const int bid = isqk ? blockIdx.x : blockIdx.x - 1856;
  const int cpx = isqk ? 232 : 116;      // sub-grid/8 (1856%8==0 keeps XCD map)
  const int swz = (bid & 7) * cpx + (bid >> 3);
  const int BNT = isqk ? 16 : 8;
  const int NF  = isqk ? 128 : 64;
  const int bm = swz / BNT, bn = swz % BNT;   // bn-fastest: A panel L2-reused
  const int m0 = bm * 128, n0 = bn * 128;
  const short* A  = isqk ? k_in : v_in;
  const short* Bw = isqk ? wqb : wvb;

  f32x4 acc[4][4] = {};
  GEMM_MAIN_LOOP();

  // epilogue
#pragma unroll
  for (int fr = 0; fr < 4; ++fr)
#pragma unroll
    for (int fc = 0; fc < 4; ++fc) {
      const int row = m0 + wr * 64 + fr * 16 + g2 * 4;
      const int colw = wc * 64 + fc * 16 + c;
      if (isqk) {                 // MODE 2: split q|k bf16 stores
        const int col2 = n0 + colw;
        short* base = (col2 < 1024) ? qbuf : kbuf;
        const int col = col2 & 1023;
#pragma unroll
        for (int j = 0; j < 4; ++j)
          base[(size_t)(row + j) * CC + col] = f2bf(acc[fr][fc][j]);
      } else {                    // MODE 3: transposed store into vt
        const int col = n0 + colw;
        const int b = row / NL;
        const int rb = row - b * NL;
        const int vtrow = (b * NH + (col >> 6)) * HD + (col & 63);
        ushort4 pk4;
        pk4.x = (unsigned short)f2bf(acc[fr][fc][0]);
        pk4.y = (unsigned short)f2bf(acc[fr][fc][1]);
        pk4.z = (unsigned short)f2bf(acc[fr][fc][2]);
        pk4.w = (unsigned short)f2bf(acc[fr][fc][3]);
        *(ushort4*)(vtb + (size_t)vtrow * NL + rb) = pk4;
      }
    }
}

// ---------------------------------------------------------------------------
// gemm_proj: final projection (MODE 1, f32 out + bias), r13/r14 proven.
// ---------------------------------------------------------------------------
__global__ __launch_bounds__(256, 4) void gemm_proj(
    const short* __restrict__ A, const short* __restrict__ Bw,
    float* __restrict__ of, const float* __restrict__ bias) {
  __shared__ short lds[16384];
  const int tid = threadIdx.x;
  const int w = tid >> 6, l = tid & 63;
  const int wr = w >> 1, wc = w & 1;
  const int c = l & 15, g2 = l >> 4;
  const int NF = 64;
  const int cpx = gridDim.x >> 3;
  const int swz = (blockIdx.x & 7) * cpx + (blockIdx.x >> 3);
  const int bm = swz / 8, bn = swz % 8;
  const int m0 = bm * 128, n0 = bn * 128;

  f32x4 acc[4][4] = {};
  GEMM_MAIN_LOOP();

#pragma unroll
  for (int fr = 0; fr < 4; ++fr)
#pragma unroll
    for (int fc = 0; fc < 4; ++fc) {
      const int row = m0 + wr * 64 + fr * 16 + g2 * 4;
      const int col = n0 + wc * 64 + fc * 16 + c;
      const float bv = bias[col];
#pragma unroll
      for (int j = 0; j < 4; ++j)
        of[(size_t)(row + j) * CC + col] = acc[fr][fc][j] + bv;
    }
}

// ---------------------------------------------------------------------------
// attn_fwd v5.1 (r11/r12/r14, proven): KVBLK=64, 4 waves x 32 q-rows, no-max
// softmax, K row-permuted + chunk-XOR swizzle, V^T likewise, 32KB LDS dbuf,
// __syncthreads() sync, uniform-exec clamped tail. grid 1792 = 8*224.
// ---------------------------------------------------------------------------
__global__ __launch_bounds__(256, 3) void attn_fwd(
    const short* __restrict__ qb, const short* __restrict__ kbuf,
    const short* __restrict__ vtb, short* __restrict__ ob) {
  __shared__ short smem[2][8192];   // per buf: K [64][64] @0, V^T [64][64] @4096
  const int tid = threadIdx.x;
  const int w = tid >> 6;           // wave 0..3
  const int l = tid & 63;
  const int c = l & 15, g = l >> 4;
  const int swzb = (blockIdx.x & 7) * 224 + (blockIdx.x >> 3);
  const int bh = swzb / 7;
  const int blk7 = swzb - bh * 7;
  const int h = bh & 15, b = bh >> 4;
  const int q0 = blk7 * 128 + w * 32;
  const bool active = q0 < NN;

  const int r = tid >> 3, ch = tid & 7;
  const int b16 = r & 15;
  const int rp = 8 * (b16 >> 2) + (b16 & 3) + 4 * (r >> 4);  // perm within 32
  const int xch = ch ^ (r & 7);
  const int tid8 = tid * 8;
  const short* srcKA = kbuf + (size_t)(b * NL + rp) * CC + h * HD + xch * 8;
  const short* srcVA = vtb + (size_t)(bh * HD + r) * NL + xch * 8;
  const short* srcVB = vtb + (size_t)(bh * HD + 32 + r) * NL + xch * 8;

  bf16x8 qf[2][2];
  if (active) {
#pragma unroll
    for (int f = 0; f < 2; ++f) {
      const short* qrow = qb + ((size_t)(b * NL + q0 + f * 16 + c) * CC + h * HD + g * 8);
      qf[f][0] = *(const bf16x8*)qrow;
      qf[f][1] = *(const bf16x8*)(qrow + 32);
    }
  }

  int xrc[2];
#pragma unroll
  for (int ks = 0; ks < 2; ++ks)
    xrc[ks] = (((ks * 4 + g) ^ (c & 7)) << 3);

  f32x4 acc[2][4] = {};
  f32x4 ellv[2] = {};

  auto STG_FULL = [&](int buf, int t) {
    GLD_LDS(srcKA + (size_t)(t * 64) * CC,      &smem[buf][tid8]);
    GLD_LDS(srcKA + (size_t)(t * 64 + 32) * CC, &smem[buf][2048 + tid8]);
    GLD_LDS(srcVA + t * 64,                     &smem[buf][4096 + tid8]);
    GLD_LDS(srcVB + t * 64,                     &smem[buf][6144 + tid8]);
  };
  auto STG_TAIL = [&](int buf) {
    GLD_LDS(srcKA + (size_t)896 * CC, &smem[buf][tid8]);   // kv 896+rp
    const int voff = (xch < 4) ? 896 : 864;   // uniform exec, clamped garbage
    GLD_LDS(srcVA + voff, &smem[buf][4096 + tid8]);
    GLD_LDS(srcVB + voff, &smem[buf][6144 + tid8]);
  };

  auto COMP_FULL = [&](const short* S) {
    bf16x8 kd[4][2], vf[4][2];
#pragma unroll
    for (int si = 0; si < 4; ++si)
#pragma unroll
      for (int ks = 0; ks < 2; ++ks)
        kd[si][ks] = *(const bf16x8*)&S[si * 1024 + c * 64 + xrc[ks]];
#pragma unroll
    for (int n = 0; n < 4; ++n)
#pragma unroll
      for (int ks = 0; ks < 2; ++ks)
        vf[n][ks] = *(const bf16x8*)&S[4096 + (n * 16 + c) * 64 + xrc[ks]];
    __builtin_amdgcn_s_setprio(1);
#pragma unroll
    for (int f = 0; f < 2; ++f) {
      f32x4 z = {0.f, 0.f, 0.f, 0.f};
      f32x4 s[4];
#pragma unroll
      for (int si = 0; si < 4; ++si) {
        s[si] = __builtin_amdgcn_mfma_f32_16x16x32_bf16(kd[si][0], qf[f][0], z, 0, 0, 0);
        s[si] = __builtin_amdgcn_mfma_f32_16x16x32_bf16(kd[si][1], qf[f][1], s[si], 0, 0, 0);
      }
      f32x4 e[4];
#pragma unroll
      for (int si = 0; si < 4; ++si)
#pragma unroll
        for (int j = 0; j < 4; ++j)
          e[si][j] = __builtin_amdgcn_exp2f(s[si][j]);
      ellv[f] += (e[0] + e[1]) + (e[2] + e[3]);
      union { bf2 h2[4]; bf16x8 v; } p0, p1;
      p0.h2[0] = bf2{(__bf16)e[0][0], (__bf16)e[0][1]};
      p0.h2[1] = bf2{(__bf16)e[0][2], (__bf16)e[0][3]};
      p0.h2[2] = bf2{(__bf16)e[1][0], (__bf16)e[1][1]};
      p0.h2[3] = bf2{(__bf16)e[1][2], (__bf16)e[1][3]};
      p1.h2[0] = bf2{(__bf16)e[2][0], (__bf16)e[2][1]};
      p1.h2[1] = bf2{(__bf16)e[2][2], (__bf16)e[2][3]};
      p1.h2[2] = bf2{(__bf16)e[3][0], (__bf16)e[3][1]};
      p1.h2[3] = bf2{(__bf16)e[3][2], (__bf16)e[3][3]};
#pragma unroll
      for (int n = 0; n < 4; ++n) {
        acc[f][n] = __builtin_amdgcn_mfma_f32_16x16x32_bf16(p0.v, vf[n][0], acc[f][n], 0, 0, 0);
        acc[f][n] = __builtin_amdgcn_mfma_f32_16x16x32_bf16(p1.v, vf[n][1], acc[f][n], 0, 0, 0);
      }
    }
    __builtin_amdgcn_s_setprio(0);
  };

  auto COMP_TAIL = [&](const short* S) {
    bf16x8 kd[2][2], vf[4];
#pragma unroll
    for (int si = 0; si < 2; ++si)
#pragma unroll
      for (int ks = 0; ks < 2; ++ks)
        kd[si][ks] = *(const bf16x8*)&S[si * 1024 + c * 64 + xrc[ks]];
#pragma unroll
    for (int n = 0; n < 4; ++n)
      vf[n] = *(const bf16x8*)&S[4096 + (n * 16 + c) * 64 + xrc[0]];
#pragma unroll
    for (int f = 0; f < 2; ++f) {
      f32x4 z = {0.f, 0.f, 0.f, 0.f};
      f32x4 s[2];
#pragma unroll
      for (int si = 0; si < 2; ++si) {
        s[si] = __builtin_amdgcn_mfma_f32_16x16x32_bf16(kd[si][0], qf[f][0], z, 0, 0, 0);
        s[si] = __builtin_amdgcn_mfma_f32_16x16x32_bf16(kd[si][1], qf[f][1], s[si], 0, 0, 0);
      }
      f32x4 e0, e1;
#pragma unroll
      for (int j = 0; j < 4; ++j) { e0[j] = __builtin_amdgcn_exp2f(s[0][j]);
                                    e1[j] = __builtin_amdgcn_exp2f(s[1][j]); }
      ellv[f] += e0 + e1;
      union { bf2 h2[4]; bf16x8 v; } p0;
      p0.h2[0] = bf2{(__bf16)e0[0], (__bf16)e0[1]};
      p0.h2[1] = bf2{(__bf16)e0[2], (__bf16)e0[3]};
      p0.h2[2] = bf2{(__bf16)e1[0], (__bf16)e1[1]};
      p0.h2[3] = bf2{(__bf16)e1[2], (__bf16)e1[3]};
#pragma unroll
      for (int n = 0; n < 4; ++n)
        acc[f][n] = __builtin_amdgcn_mfma_f32_16x16x32_bf16(p0.v, vf[n], acc[f][n], 0, 0, 0);
    }
  };

  STG_FULL(0, 0);
  __syncthreads();
  int buf = 0;
  for (int t = 0; t < 14; ++t) {
    if (t < 13) STG_FULL(buf ^ 1, t + 1);
    else        STG_TAIL(buf ^ 1);
    if (active) COMP_FULL(smem[buf]);
    __syncthreads();
    buf ^= 1;
  }
  if (active) {
    COMP_TAIL(smem[buf]);
    float rinv[2];
#pragma unroll
    for (int f = 0; f < 2; ++f) {
      float e = (ellv[f][0] + ellv[f][1]) + (ellv[f][2] + ellv[f][3]);
      e += __shfl_xor(e, 16);
      e += __shfl_xor(e, 32);
      rinv[f] = 1.0f / e;
    }
#pragma unroll
    for (int f = 0; f < 2; ++f) {
      float rj[4];
#pragma unroll
      for (int j = 0; j < 4; ++j) rj[j] = __shfl(rinv[f], g * 4 + j);
      short* orow = ob + (size_t)(b * NN + q0 + f * 16 + g * 4) * CC + h * HD + c;
#pragma unroll
      for (int n = 0; n < 4; ++n)
#pragma unroll
        for (int j = 0; j < 4; ++j)
          orow[(size_t)j * CC + n * 16] = f2bf(acc[f][n][j] * rj[j]);
    }
  }
}

// ---------------------------------------------------------------------------
extern "C" void kernel_launch(void* const* d_in, const int* in_sizes, int n_in,
                              void* d_out, int out_size, void* d_ws, size_t ws_size,
                              hipStream_t stream) {
  const float* x    = (const float*)d_in[0];
  const float* xpos = (const float*)d_in[1];
  const float* k_t  = (const float*)d_in[2];
  const float* v_t  = (const float*)d_in[3];
  const float* Wq   = (const float*)d_in[4];
  const float* Wk   = (const float*)d_in[5];
  const float* Wv   = (const float*)d_in[6];
  const float* Wp   = (const float*)d_in[7];
  const float* bp   = (const float*)d_in[8];
  float* out = (float*)d_out;

  // workspace layout (bytes), total 160,432,128
  char* ws = (char*)d_ws;
  short* k_in = (short*)ws;                       // 30,408,704  [16*928,1024] bf16
  short* v_in = (short*)(ws + 30408704);          // 30,408,704
  short* wqb  = (short*)(ws + 60817408);          // packed qk-fused, 4 MB
  short* wvb  = (short*)(ws + 65011712);          // packed Wv, 2 MB
  short* wpb  = (short*)(ws + 67108864);          // packed Wp, 2 MB
  short* qbuf = (short*)(ws + 69206016);          // 30,408,704
  short* kbuf = (short*)(ws + 99614720);          // 30,408,704
  short* vtb  = (short*)(ws + 130023424);         // 30,408,704  vt[(b*16+h)*64+d][928]
  short* attn_o = k_in;   // alias: k_in dead after fused qk GEMM

  // merged prep: blocks 0..2047 prep_w, 2048..9471 prep_kv
  prep_all<<<9472, 256, 0, stream>>>(x, xpos, k_t, v_t, Wq, Wk, Wv, Wp,
                                     k_in, v_in, wqb);
  // merged qk-projection (1856 blocks) + v-projection (928 blocks)
  gemm_qkv<<<2784, 256, 0, stream>>>(k_in, v_in, wqb, wvb, qbuf, kbuf, vtb);
  attn_fwd<<<1792, 256, 0, stream>>>(qbuf, kbuf, vtb, attn_o);
  gemm_proj<<<800, 256, 0, stream>>>(attn_o, wpb, out, bp);
}